// Round 3
// baseline (351.473 us; speedup 1.0000x reference)
//
#include <hip/hip_runtime.h>
#include <math.h>

#define NUM_HEADS   16
#define HEAD_DIM    64
#define KMAXN       64
#define LOCAL_WIN   512
#define LOG_N       17
#define LEAF_START  131072
#define MAX_LEN_TOK 65536
#define ROW         1024      // NUM_HEADS*HEAD_DIM floats per token
#define SLICE       65536     // 64 tokens * ROW floats per partial slice
#define MAXN        34

struct K1Args {
    int nNodes;
    int a[MAXN];      // start token
    int cpb[MAXN];    // chunks per block
    int C[MAXN];      // total chunks
    int CB[MAXN];     // chunk-blocks
    int K[MAXN];      // tokens kept per node (<=64)
    int off[MAXN];    // partial buffer offset (floats)
    int bbase[MAXN];  // first blockIdx for this node
};

struct K2Args {
    int nNodes;
    int K[MAXN];
    int C[MAXN];
    int CB[MAXN];
    int off[MAXN];
    int depth[MAXN];
};

__device__ __forceinline__ void f4add(float4& a, const float4& b) {
    a.x += b.x; a.y += b.y; a.z += b.z; a.w += b.w;
}

// ---------------- K1: strided chunk-sum partials, k-group tiling.
// Block = (node, kg, cb). Owns 16 consecutive k values -> per chunk reads a
// contiguous 64 KB burst (16 rows x 4 KB) with 16 independent float4 loads
// in flight per wave. 1/C applied in k1b.
__global__ __launch_bounds__(256) void k1_reduce(const float* __restrict__ v,
                                                 float* __restrict__ ws,
                                                 K1Args A) {
    int b = blockIdx.x;
    int node = 0;
    for (int i = 1; i < A.nNodes; ++i)
        if (b >= A.bbase[i]) node = i;     // uniform scalar scan
    int lb  = b - A.bbase[node];
    int CB  = A.CB[node];
    int kg  = lb / CB;
    int cb  = lb - kg * CB;
    int k0  = kg * 16;
    int K   = A.K[node];
    int RK  = K - k0; if (RK > 16) RK = 16;
    int c0  = cb * A.cpb[node];
    int c1  = c0 + A.cpb[node];
    int C   = A.C[node];
    if (c1 > C) c1 = C;

    int j = threadIdx.x;                   // float4 index within 1024-float row

    float4 acc[16];
    #pragma unroll
    for (int r = 0; r < 16; ++r) acc[r] = make_float4(0.f, 0.f, 0.f, 0.f);

    if (RK == 16) {
        for (int c = c0; c < c1; ++c) {
            const float* p = v + (long)(A.a[node] + c * 64 + k0) * ROW + j * 4;
            float4 x[16];
            #pragma unroll
            for (int r = 0; r < 16; ++r) x[r] = *(const float4*)(p + r * ROW);
            #pragma unroll
            for (int r = 0; r < 16; ++r) f4add(acc[r], x[r]);
        }
    } else {
        for (int c = c0; c < c1; ++c) {
            const float* p = v + (long)(A.a[node] + c * 64 + k0) * ROW + j * 4;
            for (int r = 0; r < RK; ++r) f4add(acc[r], *(const float4*)(p + r * ROW));
        }
    }

    float* wp = ws + (long)A.off[node] + (long)cb * SLICE + (long)k0 * ROW + j * 4;
    for (int r = 0; r < RK; ++r)
        *(float4*)(wp + (long)r * ROW) = acc[r];
}

// ---------------- K1b: reduce CB partial slices -> final f (with 1/C)
__global__ __launch_bounds__(256) void k1b_finalize(const float* __restrict__ ws_in,
                                                    float* __restrict__ f,
                                                    K2Args A) {
    int node = blockIdx.y;
    int k    = blockIdx.x;
    if (k >= A.K[node]) return;
    int CB = A.CB[node];
    const float* pf = ws_in + (long)A.off[node] + (long)k * ROW + threadIdx.x * 4;
    float4 a0 = make_float4(0.f,0.f,0.f,0.f);
    float4 a1 = a0, a2 = a0, a3 = a0;
    int cb = 0;
    for (; cb + 4 <= CB; cb += 4) {
        f4add(a0, *(const float4*)(pf + (long)cb * SLICE));
        f4add(a1, *(const float4*)(pf + (long)(cb+1) * SLICE));
        f4add(a2, *(const float4*)(pf + (long)(cb+2) * SLICE));
        f4add(a3, *(const float4*)(pf + (long)(cb+3) * SLICE));
    }
    for (; cb < CB; ++cb) f4add(a0, *(const float4*)(pf + (long)cb * SLICE));
    f4add(a0,a1); f4add(a2,a3); f4add(a0,a2);
    float invC = 1.0f / (float)A.C[node];
    a0.x*=invC; a0.y*=invC; a0.z*=invC; a0.w*=invC;
    *(float4*)(f + ((long)node * 64 + k) * ROW + threadIdx.x * 4) = a0;
}

// ---------------- K2: per-(node,head) attention over f (K <= 64), 4 waves
__global__ __launch_bounds__(256) void k2_node_attn(const float* __restrict__ f,
                                                    const float* __restrict__ q,
                                                    const float* __restrict__ W,
                                                    const float* __restrict__ temp,
                                                    float* __restrict__ node_out,
                                                    K2Args A) {
    int h    = blockIdx.x;
    int node = blockIdx.y;
    int lane = threadIdx.x & 63;           // = d
    int w    = threadIdx.x >> 6;           // wave 0..3
    int K    = A.K[node];
    int dep  = A.depth[node];
    const float* pf = f + (long)node * SLICE + h * 64;   // row k at pf + k*ROW

    __shared__ float qs[64], qds[64], sv[64], ps[64];
    __shared__ float red[4][64];

    if (threadIdx.x < 64) qs[lane] = q[h * 64 + lane];
    __syncthreads();

    float qp = 0.f;
    const float* Wr = W + ((long)dep * 64 + lane) * 64;
    #pragma unroll
    for (int e = w * 16; e < w * 16 + 16; ++e) qp += qs[e] * Wr[e];
    red[w][lane] = qp;
    __syncthreads();
    if (w == 0) qds[lane] = qs[lane] + red[0][lane] + red[1][lane] + red[2][lane] + red[3][lane];
    __syncthreads();
    float qd = qds[lane];

    float sp    = log1pf(expf(temp[dep]));
    float scale = 1.0f / ((sp + 1e-6f) * 8.0f);

    for (int k = w; k < K; k += 4) {
        float p = qd * pf[(long)k * ROW + lane];
        #pragma unroll
        for (int m = 1; m < 64; m <<= 1) p += __shfl_xor(p, m, 64);
        if (lane == 0) sv[k] = p * scale;
    }
    __syncthreads();

    if (w == 0) {
        float s  = (lane < K) ? sv[lane] : -1e30f;
        float mx = s;
        #pragma unroll
        for (int m = 1; m < 64; m <<= 1) mx = fmaxf(mx, __shfl_xor(mx, m, 64));
        float e = (lane < K) ? expf(s - mx) : 0.f;
        float S = e;
        #pragma unroll
        for (int m = 1; m < 64; m <<= 1) S += __shfl_xor(S, m, 64);
        ps[lane] = e / S;
    }
    __syncthreads();

    float o = 0.f;
    for (int k = w; k < K; k += 4) o += ps[k] * pf[(long)k * ROW + lane];
    red[w][lane] = o;
    __syncthreads();
    if (w == 0)
        node_out[node * ROW + h * 64 + lane] =
            red[0][lane] + red[1][lane] + red[2][lane] + red[3][lane];
}

// ---------------- K3: local-window attention + combine (512 thr = 8 waves/head)
__global__ __launch_bounds__(512) void k3_local(const float* __restrict__ v,
                                                const float* __restrict__ q,
                                                const float* __restrict__ node_out,
                                                int nNodes, int pos,
                                                float* __restrict__ out) {
    int h    = blockIdx.x;
    int tid  = threadIdx.x;
    int lane = tid & 63;
    int w    = tid >> 6;                   // wave 0..7
    int nloc = pos < LOCAL_WIN ? pos : LOCAL_WIN;
    int t0   = pos - nloc;

    __shared__ float qs[64];
    __shared__ float sc[LOCAL_WIN];
    __shared__ float red[8][64];
    __shared__ float wred[16];
    __shared__ float mS[2];

    if (tid < 64) qs[tid] = q[h * 64 + tid];
    __syncthreads();

    // phase A: one token per thread; serial dot over d
    float s = -1e30f;
    if (tid < nloc) {
        const float* vr = v + (long)(t0 + tid) * ROW + h * 64;
        float acc = 0.f;
        #pragma unroll 8
        for (int d = 0; d < 64; ++d) acc += qs[d] * vr[d];
        s = acc * 0.125f;
    }
    float mx = s;
    #pragma unroll
    for (int m = 1; m < 64; m <<= 1) mx = fmaxf(mx, __shfl_xor(mx, m, 64));
    if (lane == 0) wred[w] = mx;
    __syncthreads();
    if (tid == 0) {
        float m2 = wred[0];
        for (int i = 1; i < 8; ++i) m2 = fmaxf(m2, wred[i]);
        mS[0] = m2;
    }
    __syncthreads();
    float m = mS[0];

    float e = (tid < nloc) ? expf(s - m) : 0.f;
    sc[tid] = e;
    float su = e;
    #pragma unroll
    for (int mm = 1; mm < 64; mm <<= 1) su += __shfl_xor(su, mm, 64);
    if (lane == 0) wred[8 + w] = su;
    __syncthreads();
    if (tid == 0) {
        float S2 = 0.f;
        for (int i = 0; i < 8; ++i) S2 += wred[8 + i];
        mS[1] = S2;
    }
    __syncthreads();
    float S = mS[1];

    // phase B: lane = d, wave w handles tokens [w*64, w*64+64)
    float acc = 0.f;
    {
        const float* vb = v + (long)t0 * ROW + h * 64 + lane;
        int tb = w * 64;
        #pragma unroll 4
        for (int i = 0; i < 64; ++i) {
            int t = tb + i;
            if (t < nloc) acc += sc[t] * vb[(long)t * ROW];
        }
    }
    red[w][lane] = acc;
    __syncthreads();

    if (w == 0) {
        float tot = 0.f;
        #pragma unroll
        for (int i = 0; i < 8; ++i) tot += red[i][lane];
        tot = (nloc > 0) ? tot / S : 0.f;
        float tr = 0.f;
        for (int n = 0; n < nNodes; ++n) tr += node_out[n * ROW + h * 64 + lane];
        if (nNodes > 0) tr /= (float)nNodes;
        out[h * 64 + lane] = tot + tr;
    }
}

static int floor_log2_host(unsigned x) { int r = 0; while (x >>= 1) ++r; return r; }

extern "C" void kernel_launch(void* const* d_in, const int* in_sizes, int n_in,
                              void* d_out, int out_size, void* d_ws, size_t ws_size,
                              hipStream_t stream) {
    const float* v    = (const float*)d_in[0];
    const float* q    = (const float*)d_in[1];
    const float* W    = (const float*)d_in[2];
    const float* temp = (const float*)d_in[3];
    float* out        = (float*)d_out;
    float* ws         = (float*)d_ws;

    int pos = in_sizes[0] / ROW;

    int n_nodes = 0;
    int nv[MAXN], nd[MAXN];
    if (pos > 0) {
        long l = LEAF_START;
        long r = LEAF_START + (pos < MAX_LEN_TOK ? pos : MAX_LEN_TOK);
        while (l < r) {
            if (l & 1) { nv[n_nodes] = (int)l; nd[n_nodes] = LOG_N - floor_log2_host((unsigned)l); ++n_nodes; ++l; }
            if (r & 1) { --r; nv[n_nodes] = (int)r; nd[n_nodes] = LOG_N - floor_log2_host((unsigned)r); ++n_nodes; }
            l >>= 1; r >>= 1;
        }
    }

    // pick chunks-per-block: smallest (most parallelism) whose partials fit ws.
    // ws layout: partials [tot_cb*SLICE] | f [n_nodes*SLICE] | node_out [n_nodes*ROW]
    int cpb_choice = 1024;
    for (int cand : {8, 16, 32, 64, 128, 256, 512, 1024}) {
        long tot_cb = 0;
        for (int i = 0; i < n_nodes; ++i) {
            int L = 1 << nd[i];
            int C = (L > KMAXN) ? L / KMAXN : 1;
            tot_cb += (C + cand - 1) / cand;
        }
        long need = ((tot_cb + n_nodes) * (long)SLICE + (long)n_nodes * ROW) * 4;
        if (need <= (long)ws_size) { cpb_choice = cand; break; }
    }

    K1Args A1{}; K2Args A2{};
    A1.nNodes = n_nodes; A2.nNodes = n_nodes;
    int off = 0, bb = 0;
    for (int i = 0; i < n_nodes; ++i) {
        int depth = nd[i];
        int L = 1 << depth;
        int a = (nv[i] << depth) - LEAF_START;
        int K = (L < KMAXN) ? L : KMAXN;
        int C = (L > KMAXN) ? L / KMAXN : 1;
        int CB = (C + cpb_choice - 1) / cpb_choice;
        int cpb = (C + CB - 1) / CB;
        int kgc = (K + 15) / 16;
        A1.a[i] = a;   A1.cpb[i] = cpb; A1.C[i] = C; A1.CB[i] = CB; A1.K[i] = K;
        A1.off[i] = off; A1.bbase[i] = bb;
        A2.K[i] = K;   A2.C[i] = C;    A2.CB[i] = CB;
        A2.off[i] = off; A2.depth[i] = depth;
        off += CB * SLICE;
        bb  += kgc * CB;
    }
    float* f_buf     = ws + (long)off;                     // n_nodes * SLICE
    float* node_outp = f_buf + (long)n_nodes * SLICE;      // n_nodes * ROW

    if (n_nodes > 0) {
        hipLaunchKernelGGL(k1_reduce, dim3(bb), dim3(256), 0, stream, v, ws, A1);
        hipLaunchKernelGGL(k1b_finalize, dim3(64, n_nodes), dim3(256), 0, stream,
                           ws, f_buf, A2);
        hipLaunchKernelGGL(k2_node_attn, dim3(NUM_HEADS, n_nodes), dim3(256), 0, stream,
                           f_buf, q, W, temp, node_outp, A2);
    }
    hipLaunchKernelGGL(k3_local, dim3(NUM_HEADS), dim3(512), 0, stream,
                       v, q, node_outp, n_nodes, pos, out);
}

// Round 4
// 326.504 us; speedup vs baseline: 1.0765x; 1.0765x over previous
//
#include <hip/hip_runtime.h>
#include <math.h>

#define NUM_HEADS   16
#define HEAD_DIM    64
#define KMAXN       64
#define LOCAL_WIN   512
#define LOG_N       17
#define LEAF_START  131072
#define MAX_LEN_TOK 65536
#define ROW         1024      // NUM_HEADS*HEAD_DIM floats per token
#define SLICE       65536     // 64 tokens * ROW floats per partial slice
#define MAXN        34

struct K1Args {
    int nNodes;
    int a[MAXN];      // start token
    int cpb[MAXN];    // chunks per block
    int C[MAXN];      // total chunks
    int CB[MAXN];     // chunk-blocks
    int off[MAXN];    // partial buffer offset (floats)
    int bbase[MAXN];  // first blockIdx for this node
};

struct K2Args {
    int nNodes;
    int K[MAXN];
    int C[MAXN];
    int CB[MAXN];
    int off[MAXN];
    int depth[MAXN];
};

__device__ __forceinline__ void f4add(float4& a, const float4& b) {
    a.x += b.x; a.y += b.y; a.z += b.z; a.w += b.w;
}

// ---------------- K1: strided chunk-sum partials. Block = (node, k, cb).
// k-group=1 shape (R2 winner): 8 fully independent float4 loads in flight per
// wave, ~6350 short-lived blocks -> max aggregate outstanding reads.
// 1/C applied in k1b.
__global__ __launch_bounds__(256, 4) void k1_reduce(const float* __restrict__ v,
                                                    float* __restrict__ ws,
                                                    K1Args A) {
    int b = blockIdx.x;
    int node = 0;
    for (int i = 1; i < A.nNodes; ++i)
        if (b >= A.bbase[i]) node = i;     // uniform scalar scan
    int lb  = b - A.bbase[node];
    int CB  = A.CB[node];
    int k   = lb / CB;
    int cb  = lb - k * CB;
    int c0  = cb * A.cpb[node];
    int c1  = c0 + A.cpb[node];
    int C   = A.C[node];
    if (c1 > C) c1 = C;

    int j = threadIdx.x;                   // float4 index within the 1024-float row
    const float* vp = v + (long)(A.a[node] + k) * ROW + (long)c0 * SLICE + j * 4;
    const long st = (long)SLICE;           // 64 tokens

    float4 a0 = make_float4(0.f,0.f,0.f,0.f);
    float4 a1=a0,a2=a0,a3=a0,a4=a0,a5=a0,a6=a0,a7=a0;
    int c = c0;
    for (; c + 8 <= c1; c += 8) {
        float4 x0 = *(const float4*)(vp);
        float4 x1 = *(const float4*)(vp + st);
        float4 x2 = *(const float4*)(vp + 2*st);
        float4 x3 = *(const float4*)(vp + 3*st);
        float4 x4 = *(const float4*)(vp + 4*st);
        float4 x5 = *(const float4*)(vp + 5*st);
        float4 x6 = *(const float4*)(vp + 6*st);
        float4 x7 = *(const float4*)(vp + 7*st);
        f4add(a0,x0); f4add(a1,x1); f4add(a2,x2); f4add(a3,x3);
        f4add(a4,x4); f4add(a5,x5); f4add(a6,x6); f4add(a7,x7);
        vp += 8*st;
    }
    for (; c < c1; ++c) { f4add(a0, *(const float4*)(vp)); vp += st; }
    f4add(a0,a1); f4add(a2,a3); f4add(a4,a5); f4add(a6,a7);
    f4add(a0,a2); f4add(a4,a6); f4add(a0,a4);
    *(float4*)(ws + (long)A.off[node] + (long)cb * SLICE + k * ROW + j * 4) = a0;
}

// ---------------- K1b: reduce CB partial slices -> final f (with 1/C)
__global__ __launch_bounds__(256) void k1b_finalize(const float* __restrict__ ws_in,
                                                    float* __restrict__ f,
                                                    K2Args A) {
    int node = blockIdx.y;
    int k    = blockIdx.x;
    if (k >= A.K[node]) return;
    int CB = A.CB[node];
    const float* pf = ws_in + (long)A.off[node] + (long)k * ROW + threadIdx.x * 4;
    float4 a0 = make_float4(0.f,0.f,0.f,0.f);
    float4 a1 = a0, a2 = a0, a3 = a0;
    int cb = 0;
    for (; cb + 4 <= CB; cb += 4) {
        f4add(a0, *(const float4*)(pf + (long)cb * SLICE));
        f4add(a1, *(const float4*)(pf + (long)(cb+1) * SLICE));
        f4add(a2, *(const float4*)(pf + (long)(cb+2) * SLICE));
        f4add(a3, *(const float4*)(pf + (long)(cb+3) * SLICE));
    }
    for (; cb < CB; ++cb) f4add(a0, *(const float4*)(pf + (long)cb * SLICE));
    f4add(a0,a1); f4add(a2,a3); f4add(a0,a2);
    float invC = 1.0f / (float)A.C[node];
    a0.x*=invC; a0.y*=invC; a0.z*=invC; a0.w*=invC;
    *(float4*)(f + ((long)node * 64 + k) * ROW + threadIdx.x * 4) = a0;
}

// ---------------- K2: per-(node,head) attention over f (K <= 64), 4 waves
__global__ __launch_bounds__(256) void k2_node_attn(const float* __restrict__ f,
                                                    const float* __restrict__ q,
                                                    const float* __restrict__ W,
                                                    const float* __restrict__ temp,
                                                    float* __restrict__ node_out,
                                                    K2Args A) {
    int h    = blockIdx.x;
    int node = blockIdx.y;
    int lane = threadIdx.x & 63;           // = d
    int w    = threadIdx.x >> 6;           // wave 0..3
    int K    = A.K[node];
    int dep  = A.depth[node];
    const float* pf = f + (long)node * SLICE + h * 64;   // row k at pf + k*ROW

    __shared__ float qs[64], qds[64], sv[64], ps[64];
    __shared__ float red[4][64];

    if (threadIdx.x < 64) qs[lane] = q[h * 64 + lane];
    __syncthreads();

    float qp = 0.f;
    const float* Wr = W + ((long)dep * 64 + lane) * 64;
    #pragma unroll
    for (int e = w * 16; e < w * 16 + 16; ++e) qp += qs[e] * Wr[e];
    red[w][lane] = qp;
    __syncthreads();
    if (w == 0) qds[lane] = qs[lane] + red[0][lane] + red[1][lane] + red[2][lane] + red[3][lane];
    __syncthreads();
    float qd = qds[lane];

    float sp    = log1pf(expf(temp[dep]));
    float scale = 1.0f / ((sp + 1e-6f) * 8.0f);

    for (int k = w; k < K; k += 4) {
        float p = qd * pf[(long)k * ROW + lane];
        #pragma unroll
        for (int m = 1; m < 64; m <<= 1) p += __shfl_xor(p, m, 64);
        if (lane == 0) sv[k] = p * scale;
    }
    __syncthreads();

    if (w == 0) {
        float s  = (lane < K) ? sv[lane] : -1e30f;
        float mx = s;
        #pragma unroll
        for (int m = 1; m < 64; m <<= 1) mx = fmaxf(mx, __shfl_xor(mx, m, 64));
        float e = (lane < K) ? expf(s - mx) : 0.f;
        float S = e;
        #pragma unroll
        for (int m = 1; m < 64; m <<= 1) S += __shfl_xor(S, m, 64);
        ps[lane] = e / S;
    }
    __syncthreads();

    float o = 0.f;
    for (int k = w; k < K; k += 4) o += ps[k] * pf[(long)k * ROW + lane];
    red[w][lane] = o;
    __syncthreads();
    if (w == 0)
        node_out[node * ROW + h * 64 + lane] =
            red[0][lane] + red[1][lane] + red[2][lane] + red[3][lane];
}

// ---------------- K3: local-window attention + combine (512 thr = 8 waves/head)
__global__ __launch_bounds__(512) void k3_local(const float* __restrict__ v,
                                                const float* __restrict__ q,
                                                const float* __restrict__ node_out,
                                                int nNodes, int pos,
                                                float* __restrict__ out) {
    int h    = blockIdx.x;
    int tid  = threadIdx.x;
    int lane = tid & 63;
    int w    = tid >> 6;                   // wave 0..7
    int nloc = pos < LOCAL_WIN ? pos : LOCAL_WIN;
    int t0   = pos - nloc;

    __shared__ float qs[64];
    __shared__ float sc[LOCAL_WIN];
    __shared__ float red[8][64];
    __shared__ float wred[16];
    __shared__ float mS[2];

    if (tid < 64) qs[tid] = q[h * 64 + tid];
    __syncthreads();

    // phase A: one token per thread; serial dot over d
    float s = -1e30f;
    if (tid < nloc) {
        const float* vr = v + (long)(t0 + tid) * ROW + h * 64;
        float acc = 0.f;
        #pragma unroll 8
        for (int d = 0; d < 64; ++d) acc += qs[d] * vr[d];
        s = acc * 0.125f;
    }
    float mx = s;
    #pragma unroll
    for (int m = 1; m < 64; m <<= 1) mx = fmaxf(mx, __shfl_xor(mx, m, 64));
    if (lane == 0) wred[w] = mx;
    __syncthreads();
    if (tid == 0) {
        float m2 = wred[0];
        for (int i = 1; i < 8; ++i) m2 = fmaxf(m2, wred[i]);
        mS[0] = m2;
    }
    __syncthreads();
    float m = mS[0];

    float e = (tid < nloc) ? expf(s - m) : 0.f;
    sc[tid] = e;
    float su = e;
    #pragma unroll
    for (int mm = 1; mm < 64; mm <<= 1) su += __shfl_xor(su, mm, 64);
    if (lane == 0) wred[8 + w] = su;
    __syncthreads();
    if (tid == 0) {
        float S2 = 0.f;
        for (int i = 0; i < 8; ++i) S2 += wred[8 + i];
        mS[1] = S2;
    }
    __syncthreads();
    float S = mS[1];

    // phase B: lane = d, wave w handles tokens [w*64, w*64+64)
    float acc = 0.f;
    {
        const float* vb = v + (long)t0 * ROW + h * 64 + lane;
        int tb = w * 64;
        #pragma unroll 4
        for (int i = 0; i < 64; ++i) {
            int t = tb + i;
            if (t < nloc) acc += sc[t] * vb[(long)t * ROW];
        }
    }
    red[w][lane] = acc;
    __syncthreads();

    if (w == 0) {
        float tot = 0.f;
        #pragma unroll
        for (int i = 0; i < 8; ++i) tot += red[i][lane];
        tot = (nloc > 0) ? tot / S : 0.f;
        float tr = 0.f;
        for (int n = 0; n < nNodes; ++n) tr += node_out[n * ROW + h * 64 + lane];
        if (nNodes > 0) tr /= (float)nNodes;
        out[h * 64 + lane] = tot + tr;
    }
}

static int floor_log2_host(unsigned x) { int r = 0; while (x >>= 1) ++r; return r; }

extern "C" void kernel_launch(void* const* d_in, const int* in_sizes, int n_in,
                              void* d_out, int out_size, void* d_ws, size_t ws_size,
                              hipStream_t stream) {
    const float* v    = (const float*)d_in[0];
    const float* q    = (const float*)d_in[1];
    const float* W    = (const float*)d_in[2];
    const float* temp = (const float*)d_in[3];
    float* out        = (float*)d_out;
    float* ws         = (float*)d_ws;

    int pos = in_sizes[0] / ROW;

    int n_nodes = 0;
    int nv[MAXN], nd[MAXN];
    if (pos > 0) {
        long l = LEAF_START;
        long r = LEAF_START + (pos < MAX_LEN_TOK ? pos : MAX_LEN_TOK);
        while (l < r) {
            if (l & 1) { nv[n_nodes] = (int)l; nd[n_nodes] = LOG_N - floor_log2_host((unsigned)l); ++n_nodes; ++l; }
            if (r & 1) { --r; nv[n_nodes] = (int)r; nd[n_nodes] = LOG_N - floor_log2_host((unsigned)r); ++n_nodes; }
            l >>= 1; r >>= 1;
        }
    }

    // pick chunks-per-block: smallest (most blocks/waves) whose partials fit ws.
    // ws layout: partials [tot_cb*SLICE] | f [n_nodes*SLICE] | node_out [n_nodes*ROW]
    int cpb_choice = 1024;
    for (int cand : {8, 16, 32, 64, 128, 256, 512, 1024}) {
        long tot_cb = 0;
        for (int i = 0; i < n_nodes; ++i) {
            int L = 1 << nd[i];
            int C = (L > KMAXN) ? L / KMAXN : 1;
            tot_cb += (C + cand - 1) / cand;
        }
        long need = ((tot_cb + n_nodes) * (long)SLICE + (long)n_nodes * ROW) * 4;
        if (need <= (long)ws_size) { cpb_choice = cand; break; }
    }

    K1Args A1{}; K2Args A2{};
    A1.nNodes = n_nodes; A2.nNodes = n_nodes;
    int off = 0, bb = 0;
    for (int i = 0; i < n_nodes; ++i) {
        int depth = nd[i];
        int L = 1 << depth;
        int a = (nv[i] << depth) - LEAF_START;
        int K = (L < KMAXN) ? L : KMAXN;
        int C = (L > KMAXN) ? L / KMAXN : 1;
        int CB = (C + cpb_choice - 1) / cpb_choice;
        int cpb = (C + CB - 1) / CB;
        A1.a[i] = a;   A1.cpb[i] = cpb; A1.C[i] = C; A1.CB[i] = CB;
        A1.off[i] = off; A1.bbase[i] = bb;
        A2.K[i] = K;   A2.C[i] = C;    A2.CB[i] = CB;
        A2.off[i] = off; A2.depth[i] = depth;
        off += CB * SLICE;
        bb  += K * CB;              // one k-row per block (R2 winner shape)
    }
    float* f_buf     = ws + (long)off;                     // n_nodes * SLICE
    float* node_outp = f_buf + (long)n_nodes * SLICE;      // n_nodes * ROW

    if (n_nodes > 0) {
        hipLaunchKernelGGL(k1_reduce, dim3(bb), dim3(256), 0, stream, v, ws, A1);
        hipLaunchKernelGGL(k1b_finalize, dim3(64, n_nodes), dim3(256), 0, stream,
                           ws, f_buf, A2);
        hipLaunchKernelGGL(k2_node_attn, dim3(NUM_HEADS, n_nodes), dim3(256), 0, stream,
                           f_buf, q, W, temp, node_outp, A2);
    }
    hipLaunchKernelGGL(k3_local, dim3(NUM_HEADS), dim3(512), 0, stream,
                       v, q, node_outp, n_nodes, pos, out);
}

// Round 5
// 315.210 us; speedup vs baseline: 1.1150x; 1.0358x over previous
//
#include <hip/hip_runtime.h>
#include <math.h>

#define NUM_HEADS   16
#define HEAD_DIM    64
#define KMAXN       64
#define LOCAL_WIN   512
#define LOG_N       17
#define LEAF_START  131072
#define MAX_LEN_TOK 65536
#define ROW         1024      // NUM_HEADS*HEAD_DIM floats per token
#define SLICE       65536     // 64 tokens * ROW floats per partial slice
#define MAXN        34

typedef float vf4 __attribute__((ext_vector_type(4)));

__device__ __forceinline__ vf4 ntload(const float* p) {
    return __builtin_nontemporal_load((const vf4*)p);
}

struct K1Args {
    int nNodes;
    int a[MAXN];      // start token
    int cpb[MAXN];    // chunks per block
    int C[MAXN];      // total chunks
    int CB[MAXN];     // chunk-blocks
    int K[MAXN];      // kept tokens per node (<=64)
    int off[MAXN];    // partial buffer offset (floats)
    int bbase[MAXN];  // first blockIdx for this node
};

struct K2Args {
    int nNodes;
    int K[MAXN];
    int C[MAXN];
    int CB[MAXN];
    int off[MAXN];
    int depth[MAXN];
};

__device__ __forceinline__ void f4add(float4& a, const float4& b) {
    a.x += b.x; a.y += b.y; a.z += b.z; a.w += b.w;
}

// ---------------- K1: strided chunk-sum partials, streaming shape.
// Block = (node, cb, kg) with cb-MAJOR ordering: co-resident blocks read
// adjacent memory. Each block owns 4 adjacent k-rows -> per chunk one 16 KB
// contiguous burst; 2-chunk unroll = 8 independent nt-loads in flight.
// 1/C applied in k1b.
__global__ __launch_bounds__(256, 4) void k1_reduce(const float* __restrict__ v,
                                                    float* __restrict__ ws,
                                                    K1Args A) {
    int b = blockIdx.x;
    int node = 0;
    for (int i = 1; i < A.nNodes; ++i)
        if (b >= A.bbase[i]) node = i;     // uniform scalar scan
    int lb  = b - A.bbase[node];
    int K   = A.K[node];
    int kgc = (K + 3) >> 2;
    int cb  = lb / kgc;                    // cb-major
    int kg  = lb - cb * kgc;
    int k0  = kg * 4;
    int RK  = K - k0; if (RK > 4) RK = 4;
    int c0  = cb * A.cpb[node];
    int c1  = c0 + A.cpb[node];
    int C   = A.C[node];
    if (c1 > C) c1 = C;

    int j4 = threadIdx.x * 4;              // float offset of this thread's float4

    vf4 acc0 = 0.f, acc1 = 0.f, acc2 = 0.f, acc3 = 0.f;

    if (RK == 4) {
        int c = c0;
        for (; c + 2 <= c1; c += 2) {
            const float* p0 = v + (long)(A.a[node] + c * 64 + k0) * ROW + j4;
            const float* p1 = p0 + SLICE;
            vf4 y0 = ntload(p0);
            vf4 y1 = ntload(p0 + ROW);
            vf4 y2 = ntload(p0 + 2 * ROW);
            vf4 y3 = ntload(p0 + 3 * ROW);
            vf4 z0 = ntload(p1);
            vf4 z1 = ntload(p1 + ROW);
            vf4 z2 = ntload(p1 + 2 * ROW);
            vf4 z3 = ntload(p1 + 3 * ROW);
            acc0 += y0 + z0; acc1 += y1 + z1; acc2 += y2 + z2; acc3 += y3 + z3;
        }
        if (c < c1) {
            const float* p0 = v + (long)(A.a[node] + c * 64 + k0) * ROW + j4;
            acc0 += ntload(p0);
            acc1 += ntload(p0 + ROW);
            acc2 += ntload(p0 + 2 * ROW);
            acc3 += ntload(p0 + 3 * ROW);
        }
    } else {
        for (int c = c0; c < c1; ++c) {
            const float* p0 = v + (long)(A.a[node] + c * 64 + k0) * ROW + j4;
            if (RK > 0) acc0 += ntload(p0);
            if (RK > 1) acc1 += ntload(p0 + ROW);
            if (RK > 2) acc2 += ntload(p0 + 2 * ROW);
            if (RK > 3) acc3 += ntload(p0 + 3 * ROW);
        }
    }

    float* wp = ws + (long)A.off[node] + (long)cb * SLICE + (long)k0 * ROW + j4;
    if (RK > 0) *(vf4*)(wp)           = acc0;
    if (RK > 1) *(vf4*)(wp + ROW)     = acc1;
    if (RK > 2) *(vf4*)(wp + 2 * ROW) = acc2;
    if (RK > 3) *(vf4*)(wp + 3 * ROW) = acc3;
}

// ---------------- K1b: reduce CB partial slices -> final f (with 1/C)
__global__ __launch_bounds__(256) void k1b_finalize(const float* __restrict__ ws_in,
                                                    float* __restrict__ f,
                                                    K2Args A) {
    int node = blockIdx.y;
    int k    = blockIdx.x;
    if (k >= A.K[node]) return;
    int CB = A.CB[node];
    const float* pf = ws_in + (long)A.off[node] + (long)k * ROW + threadIdx.x * 4;
    float4 a0 = make_float4(0.f,0.f,0.f,0.f);
    float4 a1 = a0, a2 = a0, a3 = a0;
    int cb = 0;
    for (; cb + 4 <= CB; cb += 4) {
        f4add(a0, *(const float4*)(pf + (long)cb * SLICE));
        f4add(a1, *(const float4*)(pf + (long)(cb+1) * SLICE));
        f4add(a2, *(const float4*)(pf + (long)(cb+2) * SLICE));
        f4add(a3, *(const float4*)(pf + (long)(cb+3) * SLICE));
    }
    for (; cb < CB; ++cb) f4add(a0, *(const float4*)(pf + (long)cb * SLICE));
    f4add(a0,a1); f4add(a2,a3); f4add(a0,a2);
    float invC = 1.0f / (float)A.C[node];
    a0.x*=invC; a0.y*=invC; a0.z*=invC; a0.w*=invC;
    *(float4*)(f + ((long)node * 64 + k) * ROW + threadIdx.x * 4) = a0;
}

// ---------------- K2: per-(node,head) attention over f (K <= 64), 4 waves
__global__ __launch_bounds__(256) void k2_node_attn(const float* __restrict__ f,
                                                    const float* __restrict__ q,
                                                    const float* __restrict__ W,
                                                    const float* __restrict__ temp,
                                                    float* __restrict__ node_out,
                                                    K2Args A) {
    int h    = blockIdx.x;
    int node = blockIdx.y;
    int lane = threadIdx.x & 63;           // = d
    int w    = threadIdx.x >> 6;           // wave 0..3
    int K    = A.K[node];
    int dep  = A.depth[node];
    const float* pf = f + (long)node * SLICE + h * 64;   // row k at pf + k*ROW

    __shared__ float qs[64], qds[64], sv[64], ps[64];
    __shared__ float red[4][64];

    if (threadIdx.x < 64) qs[lane] = q[h * 64 + lane];
    __syncthreads();

    float qp = 0.f;
    const float* Wr = W + ((long)dep * 64 + lane) * 64;
    #pragma unroll
    for (int e = w * 16; e < w * 16 + 16; ++e) qp += qs[e] * Wr[e];
    red[w][lane] = qp;
    __syncthreads();
    if (w == 0) qds[lane] = qs[lane] + red[0][lane] + red[1][lane] + red[2][lane] + red[3][lane];
    __syncthreads();
    float qd = qds[lane];

    float sp    = log1pf(expf(temp[dep]));
    float scale = 1.0f / ((sp + 1e-6f) * 8.0f);

    for (int k = w; k < K; k += 4) {
        float p = qd * pf[(long)k * ROW + lane];
        #pragma unroll
        for (int m = 1; m < 64; m <<= 1) p += __shfl_xor(p, m, 64);
        if (lane == 0) sv[k] = p * scale;
    }
    __syncthreads();

    if (w == 0) {
        float s  = (lane < K) ? sv[lane] : -1e30f;
        float mx = s;
        #pragma unroll
        for (int m = 1; m < 64; m <<= 1) mx = fmaxf(mx, __shfl_xor(mx, m, 64));
        float e = (lane < K) ? expf(s - mx) : 0.f;
        float S = e;
        #pragma unroll
        for (int m = 1; m < 64; m <<= 1) S += __shfl_xor(S, m, 64);
        ps[lane] = e / S;
    }
    __syncthreads();

    float o = 0.f;
    for (int k = w; k < K; k += 4) o += ps[k] * pf[(long)k * ROW + lane];
    red[w][lane] = o;
    __syncthreads();
    if (w == 0)
        node_out[node * ROW + h * 64 + lane] =
            red[0][lane] + red[1][lane] + red[2][lane] + red[3][lane];
}

// ---------------- K3: local-window attention + combine (512 thr = 8 waves/head)
__global__ __launch_bounds__(512) void k3_local(const float* __restrict__ v,
                                                const float* __restrict__ q,
                                                const float* __restrict__ node_out,
                                                int nNodes, int pos,
                                                float* __restrict__ out) {
    int h    = blockIdx.x;
    int tid  = threadIdx.x;
    int lane = tid & 63;
    int w    = tid >> 6;                   // wave 0..7
    int nloc = pos < LOCAL_WIN ? pos : LOCAL_WIN;
    int t0   = pos - nloc;

    __shared__ float qs[64];
    __shared__ float sc[LOCAL_WIN];
    __shared__ float red[8][64];
    __shared__ float wred[16];
    __shared__ float mS[2];

    if (tid < 64) qs[tid] = q[h * 64 + tid];
    __syncthreads();

    // phase A: one token per thread; serial dot over d
    float s = -1e30f;
    if (tid < nloc) {
        const float* vr = v + (long)(t0 + tid) * ROW + h * 64;
        float acc = 0.f;
        #pragma unroll 8
        for (int d = 0; d < 64; ++d) acc += qs[d] * vr[d];
        s = acc * 0.125f;
    }
    float mx = s;
    #pragma unroll
    for (int m = 1; m < 64; m <<= 1) mx = fmaxf(mx, __shfl_xor(mx, m, 64));
    if (lane == 0) wred[w] = mx;
    __syncthreads();
    if (tid == 0) {
        float m2 = wred[0];
        for (int i = 1; i < 8; ++i) m2 = fmaxf(m2, wred[i]);
        mS[0] = m2;
    }
    __syncthreads();
    float m = mS[0];

    float e = (tid < nloc) ? expf(s - m) : 0.f;
    sc[tid] = e;
    float su = e;
    #pragma unroll
    for (int mm = 1; mm < 64; mm <<= 1) su += __shfl_xor(su, mm, 64);
    if (lane == 0) wred[8 + w] = su;
    __syncthreads();
    if (tid == 0) {
        float S2 = 0.f;
        for (int i = 0; i < 8; ++i) S2 += wred[8 + i];
        mS[1] = S2;
    }
    __syncthreads();
    float S = mS[1];

    // phase B: lane = d, wave w handles tokens [w*64, w*64+64)
    float acc = 0.f;
    {
        const float* vb = v + (long)t0 * ROW + h * 64 + lane;
        int tb = w * 64;
        #pragma unroll 4
        for (int i = 0; i < 64; ++i) {
            int t = tb + i;
            if (t < nloc) acc += sc[t] * vb[(long)t * ROW];
        }
    }
    red[w][lane] = acc;
    __syncthreads();

    if (w == 0) {
        float tot = 0.f;
        #pragma unroll
        for (int i = 0; i < 8; ++i) tot += red[i][lane];
        tot = (nloc > 0) ? tot / S : 0.f;
        float tr = 0.f;
        for (int n = 0; n < nNodes; ++n) tr += node_out[n * ROW + h * 64 + lane];
        if (nNodes > 0) tr /= (float)nNodes;
        out[h * 64 + lane] = tot + tr;
    }
}

static int floor_log2_host(unsigned x) { int r = 0; while (x >>= 1) ++r; return r; }

extern "C" void kernel_launch(void* const* d_in, const int* in_sizes, int n_in,
                              void* d_out, int out_size, void* d_ws, size_t ws_size,
                              hipStream_t stream) {
    const float* v    = (const float*)d_in[0];
    const float* q    = (const float*)d_in[1];
    const float* W    = (const float*)d_in[2];
    const float* temp = (const float*)d_in[3];
    float* out        = (float*)d_out;
    float* ws         = (float*)d_ws;

    int pos = in_sizes[0] / ROW;

    int n_nodes = 0;
    int nv[MAXN], nd[MAXN];
    if (pos > 0) {
        long l = LEAF_START;
        long r = LEAF_START + (pos < MAX_LEN_TOK ? pos : MAX_LEN_TOK);
        while (l < r) {
            if (l & 1) { nv[n_nodes] = (int)l; nd[n_nodes] = LOG_N - floor_log2_host((unsigned)l); ++n_nodes; ++l; }
            if (r & 1) { --r; nv[n_nodes] = (int)r; nd[n_nodes] = LOG_N - floor_log2_host((unsigned)r); ++n_nodes; }
            l >>= 1; r >>= 1;
        }
    }

    // pick chunks-per-block: smallest whose partials fit ws.
    // ws layout: partials [tot_cb*SLICE] | f [n_nodes*SLICE] | node_out [n_nodes*ROW]
    int cpb_choice = 1024;
    for (int cand : {8, 16, 32, 64, 128, 256, 512, 1024}) {
        long tot_cb = 0;
        for (int i = 0; i < n_nodes; ++i) {
            int L = 1 << nd[i];
            int C = (L > KMAXN) ? L / KMAXN : 1;
            tot_cb += (C + cand - 1) / cand;
        }
        long need = ((tot_cb + n_nodes) * (long)SLICE + (long)n_nodes * ROW) * 4;
        if (need <= (long)ws_size) { cpb_choice = cand; break; }
    }

    K1Args A1{}; K2Args A2{};
    A1.nNodes = n_nodes; A2.nNodes = n_nodes;
    int off = 0, bb = 0;
    for (int i = 0; i < n_nodes; ++i) {
        int depth = nd[i];
        int L = 1 << depth;
        int a = (nv[i] << depth) - LEAF_START;
        int K = (L < KMAXN) ? L : KMAXN;
        int C = (L > KMAXN) ? L / KMAXN : 1;
        int CB = (C + cpb_choice - 1) / cpb_choice;
        int cpb = (C + CB - 1) / CB;
        int kgc = (K + 3) / 4;
        A1.a[i] = a;   A1.cpb[i] = cpb; A1.C[i] = C; A1.CB[i] = CB; A1.K[i] = K;
        A1.off[i] = off; A1.bbase[i] = bb;
        A2.K[i] = K;   A2.C[i] = C;    A2.CB[i] = CB;
        A2.off[i] = off; A2.depth[i] = depth;
        off += CB * SLICE;
        bb  += kgc * CB;            // 4 k-rows per block, cb-major decode
    }
    float* f_buf     = ws + (long)off;                     // n_nodes * SLICE
    float* node_outp = f_buf + (long)n_nodes * SLICE;      // n_nodes * ROW

    if (n_nodes > 0) {
        hipLaunchKernelGGL(k1_reduce, dim3(bb), dim3(256), 0, stream, v, ws, A1);
        hipLaunchKernelGGL(k1b_finalize, dim3(64, n_nodes), dim3(256), 0, stream,
                           ws, f_buf, A2);
        hipLaunchKernelGGL(k2_node_attn, dim3(NUM_HEADS, n_nodes), dim3(256), 0, stream,
                           f_buf, q, W, temp, node_outp, A2);
    }
    hipLaunchKernelGGL(k3_local, dim3(NUM_HEADS), dim3(512), 0, stream,
                       v, q, node_outp, n_nodes, pos, out);
}